// Round 1
// baseline (545.362 us; speedup 1.0000x reference)
//
#include <hip/hip_runtime.h>
#include <math.h>

#define NB 8192
#define ND 256
#define DELTA_F 0.2f

#define BM 128
#define BN 128
#define BK 32
#define LDP 132   // padded leading dim: keeps float4 16B-aligned, A-reads conflict-free

// ---------------- normalize: inv-norms + diagonal similarity ----------------
__global__ __launch_bounds__(256) void normalize_k(
    const float* __restrict__ x, const float* __restrict__ y,
    float* __restrict__ invnx, float* __restrict__ invny, float* __restrict__ dd) {
  const int i = blockIdx.x;
  const int t = threadIdx.x;
  float xv = x[(size_t)i * ND + t];
  float yv = y[(size_t)i * ND + t];
  float sxx = xv * xv, syy = yv * yv, sxy = xv * yv;
#pragma unroll
  for (int o = 32; o > 0; o >>= 1) {
    sxx += __shfl_down(sxx, o, 64);
    syy += __shfl_down(syy, o, 64);
    sxy += __shfl_down(sxy, o, 64);
  }
  __shared__ float red[3][4];
  const int lane = t & 63, wid = t >> 6;
  if (lane == 0) { red[0][wid] = sxx; red[1][wid] = syy; red[2][wid] = sxy; }
  __syncthreads();
  if (t == 0) {
    float a = red[0][0] + red[0][1] + red[0][2] + red[0][3];
    float b = red[1][0] + red[1][1] + red[1][2] + red[1][3];
    float c = red[2][0] + red[2][1] + red[2][2] + red[2][3];
    float ix = 1.0f / sqrtf(a);
    float iy = 1.0f / sqrtf(b);
    invnx[i] = ix;
    invny[i] = iy;
    dd[i] = c * ix * iy;
  }
}

// ---------------- fused GEMM: loss partial + per-row rank counts ----------------
__global__ __launch_bounds__(256) void gemm_fused(
    const float* __restrict__ x, const float* __restrict__ y,
    const float* __restrict__ invnx, const float* __restrict__ invny,
    const float* __restrict__ dd,
    float* __restrict__ loss_accum, int* __restrict__ cnt) {
  __shared__ float Al[BK][LDP];
  __shared__ float Bl[BK][LDP];
  __shared__ int c_loc[BM];
  __shared__ float lred[4];

  const int tid = threadIdx.x;
  const int bj = blockIdx.x, bi = blockIdx.y;
  const int row0 = bi * BM, col0 = bj * BN;
  const int tx = tid & 15, ty = tid >> 4;

  for (int r = tid; r < BM; r += 256) c_loc[r] = 0;

  float acc[8][8];
#pragma unroll
  for (int m = 0; m < 8; ++m)
#pragma unroll
    for (int n = 0; n < 8; ++n) acc[m][n] = 0.f;

  // staging coordinates are K-invariant: hoist row + scale
  int srow[4], skq[4];
  float sA[4], sB[4];
#pragma unroll
  for (int v = 0; v < 4; ++v) {
    int idx = v * 256 + tid;   // 0..1023 over 128 rows x 8 float4
    srow[v] = idx >> 3;
    skq[v] = idx & 7;
    sA[v] = invnx[row0 + srow[v]];
    sB[v] = invny[col0 + srow[v]];
  }

  for (int k0 = 0; k0 < ND; k0 += BK) {
    __syncthreads();
#pragma unroll
    for (int v = 0; v < 4; ++v) {
      const int r = srow[v], kq = skq[v];
      float4 a4 = *(const float4*)&x[(size_t)(row0 + r) * ND + k0 + kq * 4];
      Al[kq * 4 + 0][r] = a4.x * sA[v];
      Al[kq * 4 + 1][r] = a4.y * sA[v];
      Al[kq * 4 + 2][r] = a4.z * sA[v];
      Al[kq * 4 + 3][r] = a4.w * sA[v];
      float4 b4 = *(const float4*)&y[(size_t)(col0 + r) * ND + k0 + kq * 4];
      Bl[kq * 4 + 0][r] = b4.x * sB[v];
      Bl[kq * 4 + 1][r] = b4.y * sB[v];
      Bl[kq * 4 + 2][r] = b4.z * sB[v];
      Bl[kq * 4 + 3][r] = b4.w * sB[v];
    }
    __syncthreads();
#pragma unroll
    for (int k = 0; k < BK; ++k) {
      float a[8], b[8];
      *(float4*)&a[0] = *(const float4*)&Al[k][ty * 8];
      *(float4*)&a[4] = *(const float4*)&Al[k][ty * 8 + 4];
      *(float4*)&b[0] = *(const float4*)&Bl[k][tx * 8];
      *(float4*)&b[4] = *(const float4*)&Bl[k][tx * 8 + 4];
#pragma unroll
      for (int m = 0; m < 8; ++m)
#pragma unroll
        for (int n = 0; n < 8; ++n)
          acc[m][n] = fmaf(a[m], b[n], acc[m][n]);
    }
  }

  // ---- epilogue: hinge-loss partials + rank counts ----
  float di[8], dj[8];
#pragma unroll
  for (int m = 0; m < 8; ++m) di[m] = dd[row0 + ty * 8 + m];
#pragma unroll
  for (int n = 0; n < 8; ++n) dj[n] = dd[col0 + tx * 8 + n];

  float lsum = 0.f;
#pragma unroll
  for (int m = 0; m < 8; ++m) {
    const int gi = row0 + ty * 8 + m;
    int cl = 0;
#pragma unroll
    for (int n = 0; n < 8; ++n) {
      const int gj = col0 + tx * 8 + n;
      const float s = acc[m][n];
      if (gi != gj) {   // diagonal excluded from BOTH loss and count
        lsum += fmaxf(0.f, s - di[m] + DELTA_F) + fmaxf(0.f, s - dj[n] + DELTA_F);
        cl += (s > di[m]) ? 1 : 0;
      }
    }
    if (cl) atomicAdd(&c_loc[ty * 8 + m], cl);
  }

#pragma unroll
  for (int o = 32; o > 0; o >>= 1) lsum += __shfl_down(lsum, o, 64);
  if ((tid & 63) == 0) lred[tid >> 6] = lsum;
  __syncthreads();
  if (tid == 0) atomicAdd(loss_accum, lred[0] + lred[1] + lred[2] + lred[3]);
  if (tid < BM) atomicAdd(&cnt[row0 + tid], c_loc[tid]);
}

// ---------------- finalize: loss scale + recall/ndcg from rank counts ----------------
__global__ __launch_bounds__(256) void finalize_k(
    const float* __restrict__ loss_accum, const int* __restrict__ cnt,
    float* __restrict__ out) {
  const int t = threadIdx.x;
  float a6[6] = {0.f, 0.f, 0.f, 0.f, 0.f, 0.f};  // r1,r5,r10,n1,n5,n10
  for (int i = t; i < NB; i += 256) {
    const int c = cnt[i];
    if (c < 10) {
      const float w = 0.69314718055994531f / logf(2.0f + (float)c);
      a6[2] += 1.f; a6[5] += w;
      if (c < 5) { a6[1] += 1.f; a6[4] += w; }
      if (c < 1) { a6[0] += 1.f; a6[3] += w; }
    }
  }
  __shared__ float red[6][4];
#pragma unroll
  for (int j = 0; j < 6; ++j) {
    float v = a6[j];
#pragma unroll
    for (int o = 32; o > 0; o >>= 1) v += __shfl_down(v, o, 64);
    if ((t & 63) == 0) red[j][t >> 6] = v;
  }
  __syncthreads();
  if (t == 0) {
    out[0] = loss_accum[0] / (float)NB;
#pragma unroll
    for (int j = 0; j < 6; ++j)
      out[1 + j] = red[j][0] + red[j][1] + red[j][2] + red[j][3];
  }
}

extern "C" void kernel_launch(void* const* d_in, const int* in_sizes, int n_in,
                              void* d_out, int out_size, void* d_ws, size_t ws_size,
                              hipStream_t stream) {
  const float* x = (const float*)d_in[0];
  const float* y = (const float*)d_in[1];
  float* out = (float*)d_out;

  char* ws = (char*)d_ws;
  float* loss_accum = (float*)ws;                       // 4 B (zeroed)
  int* cnt = (int*)(ws + 256);                          // 32 KB (zeroed)
  float* invnx = (float*)(ws + 256 + 32768);            // 32 KB
  float* invny = (float*)(ws + 256 + 2 * 32768);        // 32 KB
  float* dd = (float*)(ws + 256 + 3 * 32768);           // 32 KB

  hipMemsetAsync(ws, 0, 256 + 32768, stream);           // loss + cnt must start at 0 every call
  hipLaunchKernelGGL(normalize_k, dim3(NB), dim3(256), 0, stream, x, y, invnx, invny, dd);
  hipLaunchKernelGGL(gemm_fused, dim3(NB / BN, NB / BM), dim3(256), 0, stream,
                     x, y, invnx, invny, dd, loss_accum, cnt);
  hipLaunchKernelGGL(finalize_k, dim3(1), dim3(256), 0, stream, loss_accum, cnt, out);
}

// Round 2
// 186.453 us; speedup vs baseline: 2.9249x; 2.9249x over previous
//
#include <hip/hip_runtime.h>
#include <math.h>

#define NB 8192
#define ND 256
#define DELTA_F 0.2f

typedef __attribute__((ext_vector_type(8))) __bf16 bf16x8;
typedef __attribute__((ext_vector_type(4))) float f32x4;

// ============================================================================
// Path A (preferred): split-fp32 via bf16 MFMA. Needs ~16.1 MB workspace.
// ============================================================================

// ---- prep: row norms, diag sim, and normalized hi/lo bf16 splits ----
__global__ __launch_bounds__(256) void normalize_split_k(
    const float* __restrict__ x, const float* __restrict__ y,
    __bf16* __restrict__ Xh, __bf16* __restrict__ Xl,
    __bf16* __restrict__ Yh, __bf16* __restrict__ Yl,
    float* __restrict__ dd) {
  const int i = blockIdx.x;
  const int t = threadIdx.x;
  const size_t base = (size_t)i * ND + t;
  const float xv = x[base];
  const float yv = y[base];
  float sxx = xv * xv, syy = yv * yv, sxy = xv * yv;
#pragma unroll
  for (int o = 32; o > 0; o >>= 1) {
    sxx += __shfl_down(sxx, o, 64);
    syy += __shfl_down(syy, o, 64);
    sxy += __shfl_down(sxy, o, 64);
  }
  __shared__ float red[3][4];
  __shared__ float sh[2];
  if ((t & 63) == 0) { red[0][t >> 6] = sxx; red[1][t >> 6] = syy; red[2][t >> 6] = sxy; }
  __syncthreads();
  if (t == 0) {
    const float a = red[0][0] + red[0][1] + red[0][2] + red[0][3];
    const float b = red[1][0] + red[1][1] + red[1][2] + red[1][3];
    const float c = red[2][0] + red[2][1] + red[2][2] + red[2][3];
    const float ix = 1.0f / sqrtf(a);
    const float iy = 1.0f / sqrtf(b);
    sh[0] = ix; sh[1] = iy;
    dd[i] = c * ix * iy;
  }
  __syncthreads();
  const float xs = xv * sh[0];
  const float ys = yv * sh[1];
  const __bf16 xh = (__bf16)xs;
  const __bf16 yh = (__bf16)ys;
  Xh[base] = xh;
  Xl[base] = (__bf16)(xs - (float)xh);
  Yh[base] = yh;
  Yl[base] = (__bf16)(ys - (float)yh);
}

// ---- fused MFMA GEMM: 128x128 tile, 4 waves x (64x64), BK=32 ----
#define LDA 40  // 32 + 8 pad -> 80 B row stride: 2-way LDS conflicts only (free)

__global__ __launch_bounds__(256) void gemm_mfma(
    const __bf16* __restrict__ Xh, const __bf16* __restrict__ Xl,
    const __bf16* __restrict__ Yh, const __bf16* __restrict__ Yl,
    const float* __restrict__ dd,
    float* __restrict__ loss_accum, int* __restrict__ cnt) {
  __shared__ __align__(16) __bf16 sAh[128][LDA];
  __shared__ __align__(16) __bf16 sAl[128][LDA];
  __shared__ __align__(16) __bf16 sBh[128][LDA];
  __shared__ __align__(16) __bf16 sBl[128][LDA];
  __shared__ int c_loc[128];
  __shared__ float lred[4];

  const int tid = threadIdx.x;
  const int bj = blockIdx.x, bi = blockIdx.y;
  const int row0 = bi * 128, col0 = bj * 128;
  const int lane = tid & 63;
  const int wid = tid >> 6;
  const int wr = wid >> 1, wc = wid & 1;  // wave's 64x64 quadrant
  const int lr = lane & 15;               // frag row/col within 16
  const int lkc = lane >> 4;              // which 8-wide K-chunk / C row group

  for (int r = tid; r < 128; r += 256) c_loc[r] = 0;

  f32x4 acc[4][4];
#pragma unroll
  for (int m = 0; m < 4; ++m)
#pragma unroll
    for (int n = 0; n < 4; ++n) acc[m][n] = (f32x4)(0.0f);

  // staging: 512 16B-chunks per tile-pair row set; thread handles chunk tid and tid+256
  const int r0 = tid >> 2, kq = tid & 3;  // rows 0..63, k-quarter
  const int r1 = r0 + 64;                 // rows 64..127

  for (int k0 = 0; k0 < ND; k0 += 32) {
    __syncthreads();
    {
      const size_t ga0 = (size_t)(row0 + r0) * ND + k0 + kq * 8;
      const size_t ga1 = (size_t)(row0 + r1) * ND + k0 + kq * 8;
      const size_t gb0 = (size_t)(col0 + r0) * ND + k0 + kq * 8;
      const size_t gb1 = (size_t)(col0 + r1) * ND + k0 + kq * 8;
      *(uint4*)&sAh[r0][kq * 8] = *(const uint4*)&Xh[ga0];
      *(uint4*)&sAh[r1][kq * 8] = *(const uint4*)&Xh[ga1];
      *(uint4*)&sAl[r0][kq * 8] = *(const uint4*)&Xl[ga0];
      *(uint4*)&sAl[r1][kq * 8] = *(const uint4*)&Xl[ga1];
      *(uint4*)&sBh[r0][kq * 8] = *(const uint4*)&Yh[gb0];
      *(uint4*)&sBh[r1][kq * 8] = *(const uint4*)&Yh[gb1];
      *(uint4*)&sBl[r0][kq * 8] = *(const uint4*)&Yl[gb0];
      *(uint4*)&sBl[r1][kq * 8] = *(const uint4*)&Yl[gb1];
    }
    __syncthreads();

    const int arow = wr * 64 + lr;
    const int bcol = wc * 64 + lr;
    const int kc = lkc * 8;
    bf16x8 ah[4], al[4], bh[4], bl[4];
#pragma unroll
    for (int m = 0; m < 4; ++m) {
      ah[m] = *(const bf16x8*)&sAh[arow + m * 16][kc];
      al[m] = *(const bf16x8*)&sAl[arow + m * 16][kc];
    }
#pragma unroll
    for (int n = 0; n < 4; ++n) {
      bh[n] = *(const bf16x8*)&sBh[bcol + n * 16][kc];
      bl[n] = *(const bf16x8*)&sBl[bcol + n * 16][kc];
    }
#pragma unroll
    for (int m = 0; m < 4; ++m)
#pragma unroll
      for (int n = 0; n < 4; ++n) {
        acc[m][n] = __builtin_amdgcn_mfma_f32_16x16x32_bf16(ah[m], bh[n], acc[m][n], 0, 0, 0);
        acc[m][n] = __builtin_amdgcn_mfma_f32_16x16x32_bf16(ah[m], bl[n], acc[m][n], 0, 0, 0);
        acc[m][n] = __builtin_amdgcn_mfma_f32_16x16x32_bf16(al[m], bh[n], acc[m][n], 0, 0, 0);
      }
  }

  // ---- epilogue: hinge loss + rank counts ----
  // C/D layout (16x16x32): col = lane&15, row = (lane>>4)*4 + reg
  float djv[4];
#pragma unroll
  for (int n = 0; n < 4; ++n) djv[n] = dd[col0 + wc * 64 + n * 16 + lr];

  float lsum = 0.f;
#pragma unroll
  for (int m = 0; m < 4; ++m) {
    const int rbase = wr * 64 + m * 16 + lkc * 4;
#pragma unroll
    for (int q = 0; q < 4; ++q) {
      const int gi = row0 + rbase + q;
      const float dival = dd[gi];
      int cl = 0;
#pragma unroll
      for (int n = 0; n < 4; ++n) {
        const int gj = col0 + wc * 64 + n * 16 + lr;
        const float s = acc[m][n][q];
        if (gi != gj) {  // diagonal excluded from BOTH loss and count
          lsum += fmaxf(0.f, s - dival + DELTA_F) + fmaxf(0.f, s - djv[n] + DELTA_F);
          cl += (s > dival) ? 1 : 0;
        }
      }
      // sum over the 16 lanes (lane&15) sharing this output row
      cl += __shfl_xor(cl, 1, 64);
      cl += __shfl_xor(cl, 2, 64);
      cl += __shfl_xor(cl, 4, 64);
      cl += __shfl_xor(cl, 8, 64);
      if (lr == 0) atomicAdd(&c_loc[rbase + q], cl);
    }
  }

#pragma unroll
  for (int o = 32; o > 0; o >>= 1) lsum += __shfl_down(lsum, o, 64);
  if (lane == 0) lred[wid] = lsum;
  __syncthreads();
  if (tid == 0) atomicAdd(loss_accum, lred[0] + lred[1] + lred[2] + lred[3]);
  if (tid < 128) atomicAdd(&cnt[row0 + tid], c_loc[tid]);
}

// ============================================================================
// Path B (fallback if workspace too small): round-1 fp32 vector GEMM
// ============================================================================
#define BM 128
#define BN 128
#define LDP 132

__global__ __launch_bounds__(256) void normalize_k(
    const float* __restrict__ x, const float* __restrict__ y,
    float* __restrict__ invnx, float* __restrict__ invny, float* __restrict__ dd) {
  const int i = blockIdx.x;
  const int t = threadIdx.x;
  float xv = x[(size_t)i * ND + t];
  float yv = y[(size_t)i * ND + t];
  float sxx = xv * xv, syy = yv * yv, sxy = xv * yv;
#pragma unroll
  for (int o = 32; o > 0; o >>= 1) {
    sxx += __shfl_down(sxx, o, 64);
    syy += __shfl_down(syy, o, 64);
    sxy += __shfl_down(sxy, o, 64);
  }
  __shared__ float red[3][4];
  if ((t & 63) == 0) { red[0][t >> 6] = sxx; red[1][t >> 6] = syy; red[2][t >> 6] = sxy; }
  __syncthreads();
  if (t == 0) {
    float a = red[0][0] + red[0][1] + red[0][2] + red[0][3];
    float b = red[1][0] + red[1][1] + red[1][2] + red[1][3];
    float c = red[2][0] + red[2][1] + red[2][2] + red[2][3];
    float ix = 1.0f / sqrtf(a);
    float iy = 1.0f / sqrtf(b);
    invnx[i] = ix; invny[i] = iy; dd[i] = c * ix * iy;
  }
}

__global__ __launch_bounds__(256) void gemm_fused(
    const float* __restrict__ x, const float* __restrict__ y,
    const float* __restrict__ invnx, const float* __restrict__ invny,
    const float* __restrict__ dd,
    float* __restrict__ loss_accum, int* __restrict__ cnt) {
  __shared__ float Al[32][LDP];
  __shared__ float Bl[32][LDP];
  __shared__ int c_loc[BM];
  __shared__ float lred[4];

  const int tid = threadIdx.x;
  const int bj = blockIdx.x, bi = blockIdx.y;
  const int row0 = bi * BM, col0 = bj * BN;
  const int tx = tid & 15, ty = tid >> 4;

  for (int r = tid; r < BM; r += 256) c_loc[r] = 0;

  float acc[8][8];
#pragma unroll
  for (int m = 0; m < 8; ++m)
#pragma unroll
    for (int n = 0; n < 8; ++n) acc[m][n] = 0.f;

  int srow[4], skq[4];
  float sA[4], sB[4];
#pragma unroll
  for (int v = 0; v < 4; ++v) {
    int idx = v * 256 + tid;
    srow[v] = idx >> 3;
    skq[v] = idx & 7;
    sA[v] = invnx[row0 + srow[v]];
    sB[v] = invny[col0 + srow[v]];
  }

  for (int k0 = 0; k0 < ND; k0 += 32) {
    __syncthreads();
#pragma unroll
    for (int v = 0; v < 4; ++v) {
      const int r = srow[v], kq = skq[v];
      float4 a4 = *(const float4*)&x[(size_t)(row0 + r) * ND + k0 + kq * 4];
      Al[kq * 4 + 0][r] = a4.x * sA[v];
      Al[kq * 4 + 1][r] = a4.y * sA[v];
      Al[kq * 4 + 2][r] = a4.z * sA[v];
      Al[kq * 4 + 3][r] = a4.w * sA[v];
      float4 b4 = *(const float4*)&y[(size_t)(col0 + r) * ND + k0 + kq * 4];
      Bl[kq * 4 + 0][r] = b4.x * sB[v];
      Bl[kq * 4 + 1][r] = b4.y * sB[v];
      Bl[kq * 4 + 2][r] = b4.z * sB[v];
      Bl[kq * 4 + 3][r] = b4.w * sB[v];
    }
    __syncthreads();
#pragma unroll
    for (int k = 0; k < 32; ++k) {
      float a[8], b[8];
      *(float4*)&a[0] = *(const float4*)&Al[k][ty * 8];
      *(float4*)&a[4] = *(const float4*)&Al[k][ty * 8 + 4];
      *(float4*)&b[0] = *(const float4*)&Bl[k][tx * 8];
      *(float4*)&b[4] = *(const float4*)&Bl[k][tx * 8 + 4];
#pragma unroll
      for (int m = 0; m < 8; ++m)
#pragma unroll
        for (int n = 0; n < 8; ++n)
          acc[m][n] = fmaf(a[m], b[n], acc[m][n]);
    }
  }

  float di[8], dj[8];
#pragma unroll
  for (int m = 0; m < 8; ++m) di[m] = dd[row0 + ty * 8 + m];
#pragma unroll
  for (int n = 0; n < 8; ++n) dj[n] = dd[col0 + tx * 8 + n];

  float lsum = 0.f;
#pragma unroll
  for (int m = 0; m < 8; ++m) {
    const int gi = row0 + ty * 8 + m;
    int cl = 0;
#pragma unroll
    for (int n = 0; n < 8; ++n) {
      const int gj = col0 + tx * 8 + n;
      const float s = acc[m][n];
      if (gi != gj) {
        lsum += fmaxf(0.f, s - di[m] + DELTA_F) + fmaxf(0.f, s - dj[n] + DELTA_F);
        cl += (s > di[m]) ? 1 : 0;
      }
    }
    if (cl) atomicAdd(&c_loc[ty * 8 + m], cl);
  }

#pragma unroll
  for (int o = 32; o > 0; o >>= 1) lsum += __shfl_down(lsum, o, 64);
  if ((tid & 63) == 0) lred[tid >> 6] = lsum;
  __syncthreads();
  if (tid == 0) atomicAdd(loss_accum, lred[0] + lred[1] + lred[2] + lred[3]);
  if (tid < BM) atomicAdd(&cnt[row0 + tid], c_loc[tid]);
}

// ---------------- finalize (shared by both paths) ----------------
__global__ __launch_bounds__(256) void finalize_k(
    const float* __restrict__ loss_accum, const int* __restrict__ cnt,
    float* __restrict__ out) {
  const int t = threadIdx.x;
  float a6[6] = {0.f, 0.f, 0.f, 0.f, 0.f, 0.f};
  for (int i = t; i < NB; i += 256) {
    const int c = cnt[i];
    if (c < 10) {
      const float w = 0.69314718055994531f / logf(2.0f + (float)c);
      a6[2] += 1.f; a6[5] += w;
      if (c < 5) { a6[1] += 1.f; a6[4] += w; }
      if (c < 1) { a6[0] += 1.f; a6[3] += w; }
    }
  }
  __shared__ float red[6][4];
#pragma unroll
  for (int j = 0; j < 6; ++j) {
    float v = a6[j];
#pragma unroll
    for (int o = 32; o > 0; o >>= 1) v += __shfl_down(v, o, 64);
    if ((t & 63) == 0) red[j][t >> 6] = v;
  }
  __syncthreads();
  if (t == 0) {
    out[0] = loss_accum[0] / (float)NB;
#pragma unroll
    for (int j = 0; j < 6; ++j)
      out[1 + j] = red[j][0] + red[j][1] + red[j][2] + red[j][3];
  }
}

extern "C" void kernel_launch(void* const* d_in, const int* in_sizes, int n_in,
                              void* d_out, int out_size, void* d_ws, size_t ws_size,
                              hipStream_t stream) {
  const float* x = (const float*)d_in[0];
  const float* y = (const float*)d_in[1];
  float* out = (float*)d_out;

  char* ws = (char*)d_ws;
  float* loss_accum = (float*)ws;                    // 4 B (zeroed)
  int* cnt = (int*)(ws + 256);                       // 32 KB (zeroed)
  float* dd = (float*)(ws + 256 + 32768);            // 32 KB

  const size_t splitOff = 256 + 2 * 32768;           // 65792, 16B-aligned
  const size_t matB = (size_t)NB * ND * 2;           // 4 MB per bf16 matrix
  const size_t needA = splitOff + 4 * matB;

  hipMemsetAsync(ws, 0, 256 + 32768, stream);        // loss + cnt -> 0 every call

  if (ws_size >= needA) {
    __bf16* Xh = (__bf16*)(ws + splitOff);
    __bf16* Xl = (__bf16*)(ws + splitOff + matB);
    __bf16* Yh = (__bf16*)(ws + splitOff + 2 * matB);
    __bf16* Yl = (__bf16*)(ws + splitOff + 3 * matB);
    hipLaunchKernelGGL(normalize_split_k, dim3(NB), dim3(256), 0, stream,
                       x, y, Xh, Xl, Yh, Yl, dd);
    hipLaunchKernelGGL(gemm_mfma, dim3(NB / 128, NB / 128), dim3(256), 0, stream,
                       Xh, Xl, Yh, Yl, dd, loss_accum, cnt);
  } else {
    float* invnx = (float*)(ws + splitOff);          // reuse region (fallback fits)
    float* invny = (float*)(ws + splitOff + 32768);
    hipLaunchKernelGGL(normalize_k, dim3(NB), dim3(256), 0, stream, x, y, invnx, invny, dd);
    hipLaunchKernelGGL(gemm_fused, dim3(NB / BN, NB / BM), dim3(256), 0, stream,
                       x, y, invnx, invny, dd, loss_accum, cnt);
  }
  hipLaunchKernelGGL(finalize_k, dim3(1), dim3(256), 0, stream, loss_accum, cnt, out);
}

// Round 3
// 155.015 us; speedup vs baseline: 3.5181x; 1.2028x over previous
//
#include <hip/hip_runtime.h>
#include <math.h>

#define NB 8192
#define ND 256
#define DELTA_F 0.2f

typedef __attribute__((ext_vector_type(8))) __bf16 bf16x8;
typedef __attribute__((ext_vector_type(4))) __bf16 bf16x4;
typedef __attribute__((ext_vector_type(4))) float f32x4;

// direct global->LDS DMA, 16B per lane; global src is PER-LANE, lds dest is
// wave-uniform base + lane*16 (m97/m104 semantics)
__device__ __forceinline__ void gload16(const void* g, void* l) {
  __builtin_amdgcn_global_load_lds(
      (const __attribute__((address_space(1))) void*)g,
      (__attribute__((address_space(3))) void*)l, 16, 0, 0);
}

// ---- prep: wave-per-row norms, diag sim, normalized hi/lo bf16 splits ----
__global__ __launch_bounds__(256) void normalize_split_k(
    const float* __restrict__ x, const float* __restrict__ y,
    __bf16* __restrict__ Xh, __bf16* __restrict__ Xl,
    __bf16* __restrict__ Yh, __bf16* __restrict__ Yl,
    float* __restrict__ dd) {
  const int w = threadIdx.x >> 6, lane = threadIdx.x & 63;
  const int i = blockIdx.x * 4 + w;
  const size_t rbase = (size_t)i * ND;
  const float4 xv = *(const float4*)&x[rbase + lane * 4];
  const float4 yv = *(const float4*)&y[rbase + lane * 4];
  float sxx = xv.x * xv.x + xv.y * xv.y + xv.z * xv.z + xv.w * xv.w;
  float syy = yv.x * yv.x + yv.y * yv.y + yv.z * yv.z + yv.w * yv.w;
  float sxy = xv.x * yv.x + xv.y * yv.y + xv.z * yv.z + xv.w * yv.w;
#pragma unroll
  for (int o = 1; o < 64; o <<= 1) {   // butterfly all-reduce across the wave
    sxx += __shfl_xor(sxx, o, 64);
    syy += __shfl_xor(syy, o, 64);
    sxy += __shfl_xor(sxy, o, 64);
  }
  const float ix = 1.0f / sqrtf(sxx);
  const float iy = 1.0f / sqrtf(syy);
  if (lane == 0) dd[i] = sxy * ix * iy;

  const float xs[4] = {xv.x * ix, xv.y * ix, xv.z * ix, xv.w * ix};
  const float ys[4] = {yv.x * iy, yv.y * iy, yv.z * iy, yv.w * iy};
  bf16x4 xh, xl, yh, yl;
#pragma unroll
  for (int e = 0; e < 4; ++e) {
    const __bf16 h = (__bf16)xs[e];
    xh[e] = h; xl[e] = (__bf16)(xs[e] - (float)h);
    const __bf16 g = (__bf16)ys[e];
    yh[e] = g; yl[e] = (__bf16)(ys[e] - (float)g);
  }
  *(bf16x4*)&Xh[rbase + lane * 4] = xh;
  *(bf16x4*)&Xl[rbase + lane * 4] = xl;
  *(bf16x4*)&Yh[rbase + lane * 4] = yh;
  *(bf16x4*)&Yl[rbase + lane * 4] = yl;
}

// ---- fused MFMA GEMM: 128x128 tile, 4 waves x (64x64), BK=32,
//      global_load_lds staging with XOR-swizzled source + swizzled reads ----
__global__ __launch_bounds__(256) void gemm_mfma(
    const __bf16* __restrict__ Xh, const __bf16* __restrict__ Xl,
    const __bf16* __restrict__ Yh, const __bf16* __restrict__ Yl,
    const float* __restrict__ dd,
    float* __restrict__ loss_accum, int* __restrict__ cnt) {
  __shared__ __bf16 sT[4][128][32];   // Ah, Al, Bh, Bl — linear, 32 KB
  __shared__ int c_loc[128];
  __shared__ float lred[4];

  const int tid = threadIdx.x;
  // T1: XCD-aware swizzle (4096 blocks, 4096 % 8 == 0 -> simple form valid)
  const int lin = blockIdx.y * 64 + blockIdx.x;
  const int swz = (lin & 7) * 512 + (lin >> 3);
  const int bi = swz >> 6, bj = swz & 63;
  const int row0 = bi * 128, col0 = bj * 128;

  const int lane = tid & 63, wid = tid >> 6;
  const int wr = wid >> 1, wc = wid & 1;   // wave's 64x64 output quadrant
  const int lr = lane & 15, lkc = lane >> 4;

  for (int r = tid; r < 128; r += 256) c_loc[r] = 0;

  // staging: wave `wid` stages matrix `wid`. Lane l covers (row 16i + l/4,
  // 16B-chunk l&3) of the LDS tile; it must FETCH global chunk (l&3) ^ f(row)
  // with f(row) = (row>>1)&3 so that swizzled reads recover the original.
  const __bf16* msrc = (wid == 0) ? Xh : (wid == 1) ? Xl : (wid == 2) ? Yh : Yl;
  const int mbase = (wid < 2) ? row0 : col0;
  const int sr = lane >> 2, sc = lane & 3;
  const int ssw = sc ^ ((sr >> 1) & 3);
  const char* gp[8];
#pragma unroll
  for (int i = 0; i < 8; ++i)
    gp[i] = (const char*)msrc + (size_t)(mbase + i * 16 + sr) * (ND * 2) + ssw * 16;
  __bf16* const lbase = &sT[wid][0][0];

  f32x4 acc[4][4];
#pragma unroll
  for (int m = 0; m < 4; ++m)
#pragma unroll
    for (int n = 0; n < 4; ++n) acc[m][n] = (f32x4)(0.0f);

  const int arow = wr * 64 + lr;
  const int bcol = wc * 64 + lr;
  const int cko = (lkc ^ ((lr >> 1) & 3)) * 8;   // swizzled read chunk (2-way max)

#pragma unroll
  for (int k0 = 0; k0 < ND; k0 += 32) {
    __syncthreads();   // prev tile's reads done before overwrite
#pragma unroll
    for (int i = 0; i < 8; ++i)
      gload16(gp[i] + k0 * 2, lbase + i * 512);
    __syncthreads();   // vmcnt(0)+lgkmcnt(0) drain + barrier

    bf16x8 ah[4], al[4], bh[4], bl[4];
#pragma unroll
    for (int m = 0; m < 4; ++m) {
      ah[m] = *(const bf16x8*)&sT[0][arow + m * 16][cko];
      al[m] = *(const bf16x8*)&sT[1][arow + m * 16][cko];
    }
#pragma unroll
    for (int n = 0; n < 4; ++n) {
      bh[n] = *(const bf16x8*)&sT[2][bcol + n * 16][cko];
      bl[n] = *(const bf16x8*)&sT[3][bcol + n * 16][cko];
    }
#pragma unroll
    for (int m = 0; m < 4; ++m)
#pragma unroll
      for (int n = 0; n < 4; ++n) {
        acc[m][n] = __builtin_amdgcn_mfma_f32_16x16x32_bf16(ah[m], bh[n], acc[m][n], 0, 0, 0);
        acc[m][n] = __builtin_amdgcn_mfma_f32_16x16x32_bf16(ah[m], bl[n], acc[m][n], 0, 0, 0);
        acc[m][n] = __builtin_amdgcn_mfma_f32_16x16x32_bf16(al[m], bh[n], acc[m][n], 0, 0, 0);
      }
  }

  // ---- epilogue: hinge loss + rank counts (C/D: col=lane&15, row=(lane>>4)*4+q) ----
  float djv[4];
#pragma unroll
  for (int n = 0; n < 4; ++n) djv[n] = dd[col0 + wc * 64 + n * 16 + lr];

  float lsum = 0.f;
#pragma unroll
  for (int m = 0; m < 4; ++m) {
    const int rbase = wr * 64 + m * 16 + lkc * 4;
#pragma unroll
    for (int q = 0; q < 4; ++q) {
      const int gi = row0 + rbase + q;
      const float dival = dd[gi];
      int cl = 0;
#pragma unroll
      for (int n = 0; n < 4; ++n) {
        const int gj = col0 + wc * 64 + n * 16 + lr;
        const float s = acc[m][n][q];
        if (gi != gj) {   // diagonal excluded from BOTH loss and count
          lsum += fmaxf(0.f, s - dival + DELTA_F) + fmaxf(0.f, s - djv[n] + DELTA_F);
          cl += (s > dival) ? 1 : 0;
        }
      }
      cl += __shfl_xor(cl, 1, 64);
      cl += __shfl_xor(cl, 2, 64);
      cl += __shfl_xor(cl, 4, 64);
      cl += __shfl_xor(cl, 8, 64);
      if (lr == 0) atomicAdd(&c_loc[rbase + q], cl);
    }
  }

#pragma unroll
  for (int o = 32; o > 0; o >>= 1) lsum += __shfl_down(lsum, o, 64);
  if (lane == 0) lred[wid] = lsum;
  __syncthreads();
  if (tid == 0) atomicAdd(loss_accum, lred[0] + lred[1] + lred[2] + lred[3]);
  if (tid < 128) atomicAdd(&cnt[row0 + tid], c_loc[tid]);
}

// ---- finalize: loss scale + recall/ndcg from rank counts ----
__global__ __launch_bounds__(256) void finalize_k(
    const float* __restrict__ loss_accum, const int* __restrict__ cnt,
    float* __restrict__ out) {
  const int t = threadIdx.x;
  float a6[6] = {0.f, 0.f, 0.f, 0.f, 0.f, 0.f};
  for (int i = t; i < NB; i += 256) {
    const int c = cnt[i];
    if (c < 10) {
      const float w = 0.69314718055994531f / logf(2.0f + (float)c);
      a6[2] += 1.f; a6[5] += w;
      if (c < 5) { a6[1] += 1.f; a6[4] += w; }
      if (c < 1) { a6[0] += 1.f; a6[3] += w; }
    }
  }
  __shared__ float red[6][4];
#pragma unroll
  for (int j = 0; j < 6; ++j) {
    float v = a6[j];
#pragma unroll
    for (int o = 32; o > 0; o >>= 1) v += __shfl_down(v, o, 64);
    if ((t & 63) == 0) red[j][t >> 6] = v;
  }
  __syncthreads();
  if (t == 0) {
    out[0] = loss_accum[0] / (float)NB;
#pragma unroll
    for (int j = 0; j < 6; ++j)
      out[1 + j] = red[j][0] + red[j][1] + red[j][2] + red[j][3];
  }
}

extern "C" void kernel_launch(void* const* d_in, const int* in_sizes, int n_in,
                              void* d_out, int out_size, void* d_ws, size_t ws_size,
                              hipStream_t stream) {
  const float* x = (const float*)d_in[0];
  const float* y = (const float*)d_in[1];
  float* out = (float*)d_out;

  char* ws = (char*)d_ws;
  float* loss_accum = (float*)ws;                    // 4 B (zeroed)
  int* cnt = (int*)(ws + 256);                       // 32 KB (zeroed)
  float* dd = (float*)(ws + 256 + 32768);            // 32 KB

  const size_t splitOff = 256 + 2 * 32768;           // 16B-aligned
  const size_t matB = (size_t)NB * ND * 2;           // 4 MB per bf16 matrix
  __bf16* Xh = (__bf16*)(ws + splitOff);
  __bf16* Xl = (__bf16*)(ws + splitOff + matB);
  __bf16* Yh = (__bf16*)(ws + splitOff + 2 * matB);
  __bf16* Yl = (__bf16*)(ws + splitOff + 3 * matB);

  hipMemsetAsync(ws, 0, 256 + 32768, stream);        // loss + cnt -> 0 every call
  hipLaunchKernelGGL(normalize_split_k, dim3(NB / 4), dim3(256), 0, stream,
                     x, y, Xh, Xl, Yh, Yl, dd);
  hipLaunchKernelGGL(gemm_mfma, dim3(64, 64), dim3(256), 0, stream,
                     Xh, Xl, Yh, Yl, dd, loss_accum, cnt);
  hipLaunchKernelGGL(finalize_k, dim3(1), dim3(256), 0, stream, loss_accum, cnt, out);
}